// Round 1
// baseline (347.985 us; speedup 1.0000x reference)
//
#include <hip/hip_runtime.h>
#include <hip/hip_bf16.h>

// Problem: B=2, S=2048, E=1024, H=16, D=64. All inputs fp32, output fp32.
// Pipeline: cvt X->bf16 | transpose W->bf16 [N][K] | 3x GEMM -> Q/K/V [BH][S][D]
//           | flash attention -> AO bf16 [B*S][E] | GEMM -> out fp32 + bo.
// Workspace layout (needs 56 MiB):
//   0        Xq bf16 8MB   (reused as AO after GEMM-Q completes)
//   8MB      Xk bf16 8MB
//   16MB     Xv bf16 8MB
//   24MB     Wqt/Wkt/Wvt/Wot bf16 2MB each
//   32MB     Qb 8MB ; 40MB Kb 8MB ; 48MB Vb 8MB

#define EMBED 1024
#define NHEAD 16
#define HDIM 64
#define SEQ 2048
#define MROWS 4096  // B*S

typedef __attribute__((ext_vector_type(8))) __bf16 bf16x8;
typedef __attribute__((ext_vector_type(4))) float f32x4;

__device__ __forceinline__ unsigned short f2bf(float f) {
  unsigned int u = __builtin_bit_cast(unsigned int, f);
  u += 0x7fffu + ((u >> 16) & 1u);  // round-to-nearest-even
  return (unsigned short)(u >> 16);
}

// ---- fp32 -> bf16, 8 elements/thread ----
__global__ __launch_bounds__(256) void cvt_f32_bf16(const float* __restrict__ in,
                                                    unsigned short* __restrict__ out,
                                                    int n8) {
  int i = blockIdx.x * 256 + threadIdx.x;
  if (i >= n8) return;
  const float4* p = reinterpret_cast<const float4*>(in) + (size_t)i * 2;
  float4 a = p[0], b = p[1];
  int4 r;
  r.x = (int)f2bf(a.x) | ((int)f2bf(a.y) << 16);
  r.y = (int)f2bf(a.z) | ((int)f2bf(a.w) << 16);
  r.z = (int)f2bf(b.x) | ((int)f2bf(b.y) << 16);
  r.w = (int)f2bf(b.z) | ((int)f2bf(b.w) << 16);
  reinterpret_cast<int4*>(out)[i] = r;
}

// ---- W [K][N] fp32 -> Wt [N][K] bf16, 64x64 LDS tiles ----
__global__ __launch_bounds__(256) void wtrans(const float* __restrict__ w0, const float* __restrict__ w1,
                                              const float* __restrict__ w2, const float* __restrict__ w3,
                                              unsigned short* __restrict__ o0, unsigned short* __restrict__ o1,
                                              unsigned short* __restrict__ o2, unsigned short* __restrict__ o3) {
  __shared__ float tile[64][65];
  const float* src; unsigned short* dst;
  switch (blockIdx.z) {
    case 0: src = w0; dst = o0; break;
    case 1: src = w1; dst = o1; break;
    case 2: src = w2; dst = o2; break;
    default: src = w3; dst = o3; break;
  }
  const int k0 = blockIdx.y * 64, n0 = blockIdx.x * 64;
  const int c = threadIdx.x & 63, r0 = threadIdx.x >> 6;
#pragma unroll
  for (int i = 0; i < 16; ++i) {
    int r = r0 + i * 4;
    tile[r][c] = src[(size_t)(k0 + r) * EMBED + n0 + c];
  }
  __syncthreads();
#pragma unroll
  for (int i = 0; i < 16; ++i) {
    int nr = r0 + i * 4;
    dst[(size_t)(n0 + nr) * EMBED + k0 + c] = f2bf(tile[c][nr]);
  }
}

// ---- GEMM: C[4096x1024] = A[4096x1024] @ Bt^T + bias ----
// A bf16 row-major [M][K]; Bt bf16 [N][K].
// MODE 0: store bf16 scattered to [B*H][S][D]; MODE 1: store fp32 row-major.
template <int MODE>
__global__ __launch_bounds__(256) void gemm_bt(const unsigned short* __restrict__ A,
                                               const unsigned short* __restrict__ Bt,
                                               const float* __restrict__ bias,
                                               void* __restrict__ C) {
  constexpr int K = EMBED;
  __shared__ __align__(16) unsigned short Alds[128 * 64];
  __shared__ __align__(16) unsigned short Blds[128 * 64];
  const int tid = threadIdx.x;
  const int lane = tid & 63, w = tid >> 6;
  const int wr = w >> 1, wc = w & 1;
  const int fr = lane & 15, fq = lane >> 4;
  const int m0 = blockIdx.y * 128, n0 = blockIdx.x * 128;

  f32x4 acc[4][4];
#pragma unroll
  for (int m = 0; m < 4; ++m)
#pragma unroll
    for (int n = 0; n < 4; ++n) acc[m][n] = f32x4{0.f, 0.f, 0.f, 0.f};

  for (int k0 = 0; k0 < K; k0 += 64) {
    __syncthreads();
#pragma unroll
    for (int i = 0; i < 4; ++i) {
      int flat = (i * 256 + tid) * 8;
      int row = flat >> 6, col = flat & 63;
      *reinterpret_cast<int4*>(&Alds[flat]) =
          *reinterpret_cast<const int4*>(&A[(size_t)(m0 + row) * K + k0 + col]);
      *reinterpret_cast<int4*>(&Blds[flat]) =
          *reinterpret_cast<const int4*>(&Bt[(size_t)(n0 + row) * K + k0 + col]);
    }
    __syncthreads();
#pragma unroll
    for (int ks = 0; ks < 2; ++ks) {
      bf16x8 af[4], bfr[4];
#pragma unroll
      for (int m = 0; m < 4; ++m)
        af[m] = *reinterpret_cast<const bf16x8*>(&Alds[(wr * 64 + m * 16 + fr) * 64 + ks * 32 + fq * 8]);
#pragma unroll
      for (int n = 0; n < 4; ++n)
        bfr[n] = *reinterpret_cast<const bf16x8*>(&Blds[(wc * 64 + n * 16 + fr) * 64 + ks * 32 + fq * 8]);
#pragma unroll
      for (int m = 0; m < 4; ++m)
#pragma unroll
        for (int n = 0; n < 4; ++n)
          acc[m][n] = __builtin_amdgcn_mfma_f32_16x16x32_bf16(af[m], bfr[n], acc[m][n], 0, 0, 0);
    }
  }

#pragma unroll
  for (int n = 0; n < 4; ++n) {
    int col = n0 + wc * 64 + n * 16 + fr;
    float bv = bias[col];
#pragma unroll
    for (int m = 0; m < 4; ++m) {
      int rowb = m0 + wr * 64 + m * 16 + fq * 4;
#pragma unroll
      for (int r = 0; r < 4; ++r) {
        int row = rowb + r;
        float v = acc[m][n][r] + bv;
        if constexpr (MODE == 0) {
          int b = row >> 11, s = row & (SEQ - 1), h = col >> 6, d = col & 63;
          reinterpret_cast<unsigned short*>(C)[((size_t)((b * NHEAD + h) * SEQ + s) << 6) + d] = f2bf(v);
        } else {
          reinterpret_cast<float*>(C)[(size_t)row * EMBED + col] = v;
        }
      }
    }
  }
}

// ---- flash attention: Q,K,V bf16 [B*H][S][D] -> AO bf16 [B*S][E] ----
// 4 waves x 16 q-rows per block; KBLK=64 keys/iter; online softmax.
__global__ __launch_bounds__(256) void attn(const unsigned short* __restrict__ Q,
                                            const unsigned short* __restrict__ Kk,
                                            const unsigned short* __restrict__ V,
                                            unsigned short* __restrict__ AO) {
  __shared__ __align__(16) unsigned short Klds[64 * 64];
  __shared__ __align__(16) unsigned short Vtlds[64 * 64];  // [d][s]
  __shared__ __align__(16) unsigned short Plds[4][16 * 64];
  const int tid = threadIdx.x, lane = tid & 63, w = tid >> 6;
  const int fr = lane & 15, fq = lane >> 4;
  const int head = blockIdx.y;
  const int q0 = blockIdx.x * 64;
  const size_t hb = (size_t)head * SEQ * HDIM;
  const unsigned short* Qh = Q + hb;
  const unsigned short* Kh = Kk + hb;
  const unsigned short* Vh = V + hb;

  bf16x8 qf[2];
  {
    size_t qoff = (size_t)(q0 + w * 16 + fr) * HDIM + fq * 8;
    qf[0] = *reinterpret_cast<const bf16x8*>(&Qh[qoff]);
    qf[1] = *reinterpret_cast<const bf16x8*>(&Qh[qoff + 32]);
  }
  f32x4 oacc[4];
#pragma unroll
  for (int n = 0; n < 4; ++n) oacc[n] = f32x4{0.f, 0.f, 0.f, 0.f};
  float mrow[4] = {-1e30f, -1e30f, -1e30f, -1e30f};
  float lrow[4] = {0.f, 0.f, 0.f, 0.f};
  const float scale = 0.125f;  // 1/sqrt(64)

  for (int kt = 0; kt < SEQ / 64; ++kt) {
    __syncthreads();
#pragma unroll
    for (int i = 0; i < 2; ++i) {
      int flat = (i * 256 + tid) * 8;
      int row = flat >> 6, col = flat & 63;
      *reinterpret_cast<int4*>(&Klds[flat]) =
          *reinterpret_cast<const int4*>(&Kh[(size_t)(kt * 64 + row) * HDIM + col]);
      int4 raw = *reinterpret_cast<const int4*>(&Vh[(size_t)(kt * 64 + row) * HDIM + col]);
      const unsigned short* e = reinterpret_cast<const unsigned short*>(&raw);
#pragma unroll
      for (int j = 0; j < 8; ++j) Vtlds[(col + j) * 64 + row] = e[j];
    }
    __syncthreads();

    // QK^T: scores [16 q][64 k] per wave
    f32x4 sc[4];
#pragma unroll
    for (int n = 0; n < 4; ++n) {
      f32x4 a = f32x4{0.f, 0.f, 0.f, 0.f};
      bf16x8 b0 = *reinterpret_cast<const bf16x8*>(&Klds[(n * 16 + fr) * 64 + fq * 8]);
      bf16x8 b1 = *reinterpret_cast<const bf16x8*>(&Klds[(n * 16 + fr) * 64 + 32 + fq * 8]);
      a = __builtin_amdgcn_mfma_f32_16x16x32_bf16(qf[0], b0, a, 0, 0, 0);
      a = __builtin_amdgcn_mfma_f32_16x16x32_bf16(qf[1], b1, a, 0, 0, 0);
      sc[n] = a;
    }

    // online softmax; row r lives in 16-lane group (same fq)
    float p[4][4];
#pragma unroll
    for (int r = 0; r < 4; ++r) {
      float s0 = sc[0][r] * scale, s1 = sc[1][r] * scale;
      float s2 = sc[2][r] * scale, s3 = sc[3][r] * scale;
      float mt = fmaxf(fmaxf(s0, s1), fmaxf(s2, s3));
#pragma unroll
      for (int msk = 1; msk < 16; msk <<= 1) mt = fmaxf(mt, __shfl_xor(mt, msk, 16));
      float mn = fmaxf(mrow[r], mt);
      float resc = expf(mrow[r] - mn);
      float p0 = expf(s0 - mn), p1 = expf(s1 - mn), p2 = expf(s2 - mn), p3 = expf(s3 - mn);
      p[0][r] = p0; p[1][r] = p1; p[2][r] = p2; p[3][r] = p3;
      float ps = p0 + p1 + p2 + p3;
#pragma unroll
      for (int msk = 1; msk < 16; msk <<= 1) ps += __shfl_xor(ps, msk, 16);
      lrow[r] = lrow[r] * resc + ps;
      mrow[r] = mn;
#pragma unroll
      for (int n = 0; n < 4; ++n) oacc[n][r] *= resc;
    }

    // P -> LDS (per-wave), re-read in A-fragment layout
#pragma unroll
    for (int n = 0; n < 4; ++n)
#pragma unroll
      for (int r = 0; r < 4; ++r)
        Plds[w][(fq * 4 + r) * 64 + n * 16 + fr] = f2bf(p[n][r]);
    __syncthreads();

    bf16x8 pa0 = *reinterpret_cast<const bf16x8*>(&Plds[w][fr * 64 + fq * 8]);
    bf16x8 pa1 = *reinterpret_cast<const bf16x8*>(&Plds[w][fr * 64 + 32 + fq * 8]);
#pragma unroll
    for (int n = 0; n < 4; ++n) {
      bf16x8 vb0 = *reinterpret_cast<const bf16x8*>(&Vtlds[(n * 16 + fr) * 64 + fq * 8]);
      bf16x8 vb1 = *reinterpret_cast<const bf16x8*>(&Vtlds[(n * 16 + fr) * 64 + 32 + fq * 8]);
      oacc[n] = __builtin_amdgcn_mfma_f32_16x16x32_bf16(pa0, vb0, oacc[n], 0, 0, 0);
      oacc[n] = __builtin_amdgcn_mfma_f32_16x16x32_bf16(pa1, vb1, oacc[n], 0, 0, 0);
    }
  }

  const int b = head >> 4, h = head & 15;
#pragma unroll
  for (int r = 0; r < 4; ++r) {
    float inv = 1.0f / lrow[r];
    int srow = q0 + w * 16 + fq * 4 + r;
    size_t ob = (size_t)(b * SEQ + srow) * EMBED + h * 64;
#pragma unroll
    for (int n = 0; n < 4; ++n) AO[ob + n * 16 + fr] = f2bf(oacc[n][r] * inv);
  }
}

extern "C" void kernel_launch(void* const* d_in, const int* in_sizes, int n_in,
                              void* d_out, int out_size, void* d_ws, size_t ws_size,
                              hipStream_t stream) {
  const float* q32 = (const float*)d_in[0];
  const float* k32 = (const float*)d_in[1];
  const float* v32 = (const float*)d_in[2];
  const float* Wq = (const float*)d_in[3]; const float* bq = (const float*)d_in[4];
  const float* Wk = (const float*)d_in[5]; const float* bk = (const float*)d_in[6];
  const float* Wv = (const float*)d_in[7]; const float* bv = (const float*)d_in[8];
  const float* Wo = (const float*)d_in[9]; const float* bo = (const float*)d_in[10];
  float* out = (float*)d_out;

  char* ws = (char*)d_ws;
  const size_t MB = 1u << 20;
  unsigned short* Xq  = (unsigned short*)(ws + 0 * MB);
  unsigned short* Xk  = (unsigned short*)(ws + 8 * MB);
  unsigned short* Xv  = (unsigned short*)(ws + 16 * MB);
  unsigned short* Wqt = (unsigned short*)(ws + 24 * MB);
  unsigned short* Wkt = (unsigned short*)(ws + 26 * MB);
  unsigned short* Wvt = (unsigned short*)(ws + 28 * MB);
  unsigned short* Wot = (unsigned short*)(ws + 30 * MB);
  unsigned short* Qb  = (unsigned short*)(ws + 32 * MB);
  unsigned short* Kb  = (unsigned short*)(ws + 40 * MB);
  unsigned short* Vb  = (unsigned short*)(ws + 48 * MB);
  unsigned short* AO  = Xq;  // safe: GEMM-Q (sole Xq reader) completes before attn writes

  const int n8 = (MROWS * EMBED) / 8;  // 524288
  cvt_f32_bf16<<<n8 / 256, 256, 0, stream>>>(q32, Xq, n8);
  cvt_f32_bf16<<<n8 / 256, 256, 0, stream>>>(k32, Xk, n8);
  cvt_f32_bf16<<<n8 / 256, 256, 0, stream>>>(v32, Xv, n8);
  wtrans<<<dim3(16, 16, 4), 256, 0, stream>>>(Wq, Wk, Wv, Wo, Wqt, Wkt, Wvt, Wot);

  dim3 gg(EMBED / 128, MROWS / 128);  // (8, 32)
  gemm_bt<0><<<gg, 256, 0, stream>>>(Xq, Wqt, bq, Qb);
  gemm_bt<0><<<gg, 256, 0, stream>>>(Xk, Wkt, bk, Kb);
  gemm_bt<0><<<gg, 256, 0, stream>>>(Xv, Wvt, bv, Vb);

  attn<<<dim3(SEQ / 64, 32), 256, 0, stream>>>(Qb, Kb, Vb, AO);

  gemm_bt<1><<<gg, 256, 0, stream>>>(AO, Wot, bo, out);
}

// Round 2
// 222.885 us; speedup vs baseline: 1.5613x; 1.5613x over previous
//
#include <hip/hip_runtime.h>
#include <hip/hip_bf16.h>

// Problem: B=2, S=2048, E=1024, H=16, D=64. All inputs fp32, output fp32.
// Pipeline: cvt X->bf16 | transpose W->bf16 [N][K] | GEMM-Q/K -> [BH][S][D],
//           GEMM-V -> V^T [BH][D][S] | flash attention -> AO bf16 [B*S][E]
//           | GEMM -> out fp32 + bo.
// All LDS tiles use the T2 XOR swizzle: byte ^= ((row&7)<<4) within 128B rows.
// Workspace layout (needs 56 MiB):
//   0    Xq 8MB (reused as AO) | 8MB Xk | 16MB Xv | 24..32MB Wqt/Wkt/Wvt/Wot
//   32MB Qb | 40MB Kb | 48MB Vt

#define EMBED 1024
#define NHEAD 16
#define HDIM 64
#define SEQ 2048
#define MROWS 4096  // B*S

typedef __attribute__((ext_vector_type(8))) __bf16 bf16x8;
typedef __attribute__((ext_vector_type(4))) float f32x4;

__device__ __forceinline__ unsigned short f2bf(float f) {
  unsigned int u = __builtin_bit_cast(unsigned int, f);
  u += 0x7fffu + ((u >> 16) & 1u);  // round-to-nearest-even
  return (unsigned short)(u >> 16);
}

// swizzled byte offset within a [rows][128B] LDS tile
__device__ __forceinline__ int swz(int row, int bcol) {
  return row * 128 + (bcol ^ ((row & 7) << 4));
}

// ---- fp32 -> bf16, 8 elements/thread; blockIdx.y selects src/dst ----
__global__ __launch_bounds__(256) void cvt_f32_bf16(const float* __restrict__ i0, const float* __restrict__ i1,
                                                    const float* __restrict__ i2,
                                                    unsigned short* __restrict__ o0, unsigned short* __restrict__ o1,
                                                    unsigned short* __restrict__ o2) {
  const float* in; unsigned short* out;
  switch (blockIdx.y) {
    case 0: in = i0; out = o0; break;
    case 1: in = i1; out = o1; break;
    default: in = i2; out = o2; break;
  }
  int i = blockIdx.x * 256 + threadIdx.x;
  const float4* p = reinterpret_cast<const float4*>(in) + (size_t)i * 2;
  float4 a = p[0], b = p[1];
  int4 r;
  r.x = (int)f2bf(a.x) | ((int)f2bf(a.y) << 16);
  r.y = (int)f2bf(a.z) | ((int)f2bf(a.w) << 16);
  r.z = (int)f2bf(b.x) | ((int)f2bf(b.y) << 16);
  r.w = (int)f2bf(b.z) | ((int)f2bf(b.w) << 16);
  reinterpret_cast<int4*>(out)[i] = r;
}

// ---- W [K][N] fp32 -> Wt [N][K] bf16, 64x64 LDS tiles ----
__global__ __launch_bounds__(256) void wtrans(const float* __restrict__ w0, const float* __restrict__ w1,
                                              const float* __restrict__ w2, const float* __restrict__ w3,
                                              unsigned short* __restrict__ o0, unsigned short* __restrict__ o1,
                                              unsigned short* __restrict__ o2, unsigned short* __restrict__ o3) {
  __shared__ float tile[64][65];
  const float* src; unsigned short* dst;
  switch (blockIdx.z) {
    case 0: src = w0; dst = o0; break;
    case 1: src = w1; dst = o1; break;
    case 2: src = w2; dst = o2; break;
    default: src = w3; dst = o3; break;
  }
  const int k0 = blockIdx.y * 64, n0 = blockIdx.x * 64;
  const int c = threadIdx.x & 63, r0 = threadIdx.x >> 6;
#pragma unroll
  for (int i = 0; i < 16; ++i) {
    int r = r0 + i * 4;
    tile[r][c] = src[(size_t)(k0 + r) * EMBED + n0 + c];
  }
  __syncthreads();
#pragma unroll
  for (int i = 0; i < 16; ++i) {
    int nr = r0 + i * 4;
    dst[(size_t)(n0 + nr) * EMBED + k0 + c] = f2bf(tile[c][nr]);
  }
}

// ---- GEMM: C[4096x1024] = A[4096x1024] @ Bt^T + bias, then *oscale ----
// A bf16 row-major [M][K]; Bt bf16 [N][K].
// MODE 0: bf16 scatter to [B*H][S][D] (Q with oscale=0.125, K with 1.0)
// MODE 1: fp32 row-major (final output)
// MODE 2: bf16 V^T scatter to [B*H][D][S], 4 s-packed per 8B store
template <int MODE>
__global__ __launch_bounds__(256) void gemm_bt(const unsigned short* __restrict__ A,
                                               const unsigned short* __restrict__ Bt,
                                               const float* __restrict__ bias,
                                               void* __restrict__ C, float oscale) {
  constexpr int K = EMBED;
  __shared__ __align__(16) unsigned short Alds[128 * 64];
  __shared__ __align__(16) unsigned short Blds[128 * 64];
  char* Ab8 = (char*)Alds; char* Bb8 = (char*)Blds;
  const int tid = threadIdx.x;
  const int lane = tid & 63, w = tid >> 6;
  const int wr = w >> 1, wc = w & 1;
  const int fr = lane & 15, fq = lane >> 4;
  const int m0 = blockIdx.y * 128, n0 = blockIdx.x * 128;

  f32x4 acc[4][4];
#pragma unroll
  for (int m = 0; m < 4; ++m)
#pragma unroll
    for (int n = 0; n < 4; ++n) acc[m][n] = f32x4{0.f, 0.f, 0.f, 0.f};

  for (int k0 = 0; k0 < K; k0 += 64) {
    __syncthreads();
#pragma unroll
    for (int i = 0; i < 4; ++i) {
      int flat = (i * 256 + tid) * 8;
      int row = flat >> 6, col = flat & 63;
      int dst = swz(row, col * 2);
      *reinterpret_cast<int4*>(Ab8 + dst) =
          *reinterpret_cast<const int4*>(&A[(size_t)(m0 + row) * K + k0 + col]);
      *reinterpret_cast<int4*>(Bb8 + dst) =
          *reinterpret_cast<const int4*>(&Bt[(size_t)(n0 + row) * K + k0 + col]);
    }
    __syncthreads();
#pragma unroll
    for (int ks = 0; ks < 2; ++ks) {
      bf16x8 af[4], bfr[4];
#pragma unroll
      for (int m = 0; m < 4; ++m) {
        int ar = wr * 64 + m * 16 + fr;
        af[m] = *reinterpret_cast<const bf16x8*>(Ab8 + swz(ar, ks * 64 + fq * 16));
      }
#pragma unroll
      for (int n = 0; n < 4; ++n) {
        int br = wc * 64 + n * 16 + fr;
        bfr[n] = *reinterpret_cast<const bf16x8*>(Bb8 + swz(br, ks * 64 + fq * 16));
      }
#pragma unroll
      for (int m = 0; m < 4; ++m)
#pragma unroll
        for (int n = 0; n < 4; ++n)
          acc[m][n] = __builtin_amdgcn_mfma_f32_16x16x32_bf16(af[m], bfr[n], acc[m][n], 0, 0, 0);
    }
  }

#pragma unroll
  for (int n = 0; n < 4; ++n) {
    int col = n0 + wc * 64 + n * 16 + fr;
    float bv = bias[col];
#pragma unroll
    for (int m = 0; m < 4; ++m) {
      int rowb = m0 + wr * 64 + m * 16 + fq * 4;
      if constexpr (MODE == 2) {
        int b = rowb >> 11, s0 = rowb & (SEQ - 1);
        int h = col >> 6, d = col & 63;
        int2 pk;
        unsigned short e0 = f2bf((acc[m][n][0] + bv) * oscale);
        unsigned short e1 = f2bf((acc[m][n][1] + bv) * oscale);
        unsigned short e2 = f2bf((acc[m][n][2] + bv) * oscale);
        unsigned short e3 = f2bf((acc[m][n][3] + bv) * oscale);
        pk.x = (int)e0 | ((int)e1 << 16);
        pk.y = (int)e2 | ((int)e3 << 16);
        *reinterpret_cast<int2*>(
            &reinterpret_cast<unsigned short*>(C)[((size_t)((b * NHEAD + h) * HDIM + d)) * SEQ + s0]) = pk;
      } else {
#pragma unroll
        for (int r = 0; r < 4; ++r) {
          int row = rowb + r;
          float v = (acc[m][n][r] + bv) * oscale;
          if constexpr (MODE == 0) {
            int b = row >> 11, s = row & (SEQ - 1), h = col >> 6, d = col & 63;
            reinterpret_cast<unsigned short*>(C)[((size_t)((b * NHEAD + h) * SEQ + s) << 6) + d] = f2bf(v);
          } else {
            reinterpret_cast<float*>(C)[(size_t)row * EMBED + col] = v;
          }
        }
      }
    }
  }
}

// ---- flash attention ----
// Q,K bf16 [B*H][S][D] (Q pre-scaled by 1/8); Vt bf16 [B*H][D][S].
// 4 waves x 16 q-rows per block; KBLK=64 keys/iter; online softmax.
// All LDS tiles swizzled (T2).
__global__ __launch_bounds__(256) void attn(const unsigned short* __restrict__ Q,
                                            const unsigned short* __restrict__ Kk,
                                            const unsigned short* __restrict__ Vt,
                                            unsigned short* __restrict__ AO) {
  __shared__ __align__(16) unsigned short Klds[64 * 64];
  __shared__ __align__(16) unsigned short Vlds[64 * 64];  // [d][k]
  __shared__ __align__(16) unsigned short Plds[4][16 * 64];
  char* Kb8 = (char*)Klds;
  char* Vb8 = (char*)Vlds;
  const int tid = threadIdx.x, lane = tid & 63, w = tid >> 6;
  const int fr = lane & 15, fq = lane >> 4;
  char* Pb8 = (char*)&Plds[w][0];
  const int head = blockIdx.y;
  const int q0 = blockIdx.x * 64;
  const size_t hb = (size_t)head * SEQ * HDIM;
  const unsigned short* Qh = Q + hb;
  const unsigned short* Kh = Kk + hb;
  const unsigned short* Vh = Vt + hb;  // [d][s]

  bf16x8 qf[2];
  {
    size_t qoff = (size_t)(q0 + w * 16 + fr) * HDIM + fq * 8;
    qf[0] = *reinterpret_cast<const bf16x8*>(&Qh[qoff]);
    qf[1] = *reinterpret_cast<const bf16x8*>(&Qh[qoff + 32]);
  }
  f32x4 oacc[4];
#pragma unroll
  for (int n = 0; n < 4; ++n) oacc[n] = f32x4{0.f, 0.f, 0.f, 0.f};
  float mrow[4] = {-1e30f, -1e30f, -1e30f, -1e30f};
  float lrow[4] = {0.f, 0.f, 0.f, 0.f};

  for (int kt = 0; kt < SEQ / 64; ++kt) {
    __syncthreads();
#pragma unroll
    for (int i = 0; i < 2; ++i) {
      int flat = (i * 256 + tid) * 8;
      int row = flat >> 6, col = flat & 63;
      int dst = swz(row, col * 2);
      *reinterpret_cast<int4*>(Kb8 + dst) =
          *reinterpret_cast<const int4*>(&Kh[(size_t)(kt * 64 + row) * HDIM + col]);
      *reinterpret_cast<int4*>(Vb8 + dst) =
          *reinterpret_cast<const int4*>(&Vh[(size_t)row * SEQ + kt * 64 + col]);
    }
    __syncthreads();

    // QK^T: scores [16 q][64 k] per wave (Q pre-scaled by 1/8)
    f32x4 sc[4];
#pragma unroll
    for (int n = 0; n < 4; ++n) {
      int kr = n * 16 + fr;
      f32x4 a = f32x4{0.f, 0.f, 0.f, 0.f};
      bf16x8 b0 = *reinterpret_cast<const bf16x8*>(Kb8 + swz(kr, fq * 16));
      bf16x8 b1 = *reinterpret_cast<const bf16x8*>(Kb8 + swz(kr, 64 + fq * 16));
      a = __builtin_amdgcn_mfma_f32_16x16x32_bf16(qf[0], b0, a, 0, 0, 0);
      a = __builtin_amdgcn_mfma_f32_16x16x32_bf16(qf[1], b1, a, 0, 0, 0);
      sc[n] = a;
    }

    // online softmax; q-row r lives in the 16-lane group (same fq)
    float p[4][4];
#pragma unroll
    for (int r = 0; r < 4; ++r) {
      float s0 = sc[0][r], s1 = sc[1][r], s2 = sc[2][r], s3 = sc[3][r];
      float mt = fmaxf(fmaxf(s0, s1), fmaxf(s2, s3));
#pragma unroll
      for (int msk = 1; msk < 16; msk <<= 1) mt = fmaxf(mt, __shfl_xor(mt, msk, 16));
      float mn = fmaxf(mrow[r], mt);
      float resc = __expf(mrow[r] - mn);
      float p0 = __expf(s0 - mn), p1 = __expf(s1 - mn), p2 = __expf(s2 - mn), p3 = __expf(s3 - mn);
      p[0][r] = p0; p[1][r] = p1; p[2][r] = p2; p[3][r] = p3;
      float ps = p0 + p1 + p2 + p3;
#pragma unroll
      for (int msk = 1; msk < 16; msk <<= 1) ps += __shfl_xor(ps, msk, 16);
      lrow[r] = lrow[r] * resc + ps;
      mrow[r] = mn;
#pragma unroll
      for (int n = 0; n < 4; ++n) oacc[n][r] *= resc;
    }

    // P -> per-wave LDS (swizzled), re-read in A-fragment layout.
    // Same-wave write->read: no barrier needed (compiler inserts lgkmcnt).
#pragma unroll
    for (int n = 0; n < 4; ++n)
#pragma unroll
      for (int r = 0; r < 4; ++r) {
        int row = fq * 4 + r;
        *reinterpret_cast<unsigned short*>(Pb8 + swz(row, (n * 16 + fr) * 2)) = f2bf(p[n][r]);
      }

    bf16x8 pa0 = *reinterpret_cast<const bf16x8*>(Pb8 + swz(fr, fq * 16));
    bf16x8 pa1 = *reinterpret_cast<const bf16x8*>(Pb8 + swz(fr, 64 + fq * 16));
#pragma unroll
    for (int n = 0; n < 4; ++n) {
      int dr = n * 16 + fr;
      bf16x8 vb0 = *reinterpret_cast<const bf16x8*>(Vb8 + swz(dr, fq * 16));
      bf16x8 vb1 = *reinterpret_cast<const bf16x8*>(Vb8 + swz(dr, 64 + fq * 16));
      oacc[n] = __builtin_amdgcn_mfma_f32_16x16x32_bf16(pa0, vb0, oacc[n], 0, 0, 0);
      oacc[n] = __builtin_amdgcn_mfma_f32_16x16x32_bf16(pa1, vb1, oacc[n], 0, 0, 0);
    }
  }

  const int b = head >> 4, h = head & 15;
#pragma unroll
  for (int r = 0; r < 4; ++r) {
    float inv = 1.0f / lrow[r];
    int srow = q0 + w * 16 + fq * 4 + r;
    size_t ob = (size_t)(b * SEQ + srow) * EMBED + h * 64;
#pragma unroll
    for (int n = 0; n < 4; ++n) AO[ob + n * 16 + fr] = f2bf(oacc[n][r] * inv);
  }
}

extern "C" void kernel_launch(void* const* d_in, const int* in_sizes, int n_in,
                              void* d_out, int out_size, void* d_ws, size_t ws_size,
                              hipStream_t stream) {
  const float* q32 = (const float*)d_in[0];
  const float* k32 = (const float*)d_in[1];
  const float* v32 = (const float*)d_in[2];
  const float* Wq = (const float*)d_in[3]; const float* bq = (const float*)d_in[4];
  const float* Wk = (const float*)d_in[5]; const float* bk = (const float*)d_in[6];
  const float* Wv = (const float*)d_in[7]; const float* bv = (const float*)d_in[8];
  const float* Wo = (const float*)d_in[9]; const float* bo = (const float*)d_in[10];
  float* out = (float*)d_out;

  char* ws = (char*)d_ws;
  const size_t MB = 1u << 20;
  unsigned short* Xq  = (unsigned short*)(ws + 0 * MB);
  unsigned short* Xk  = (unsigned short*)(ws + 8 * MB);
  unsigned short* Xv  = (unsigned short*)(ws + 16 * MB);
  unsigned short* Wqt = (unsigned short*)(ws + 24 * MB);
  unsigned short* Wkt = (unsigned short*)(ws + 26 * MB);
  unsigned short* Wvt = (unsigned short*)(ws + 28 * MB);
  unsigned short* Wot = (unsigned short*)(ws + 30 * MB);
  unsigned short* Qb  = (unsigned short*)(ws + 32 * MB);
  unsigned short* Kb  = (unsigned short*)(ws + 40 * MB);
  unsigned short* Vtb = (unsigned short*)(ws + 48 * MB);
  unsigned short* AO  = Xq;  // safe: GEMM-Q (sole Xq reader) completes before attn writes

  const int n8 = (MROWS * EMBED) / 8;  // 524288
  cvt_f32_bf16<<<dim3(n8 / 256, 3), 256, 0, stream>>>(q32, k32, v32, Xq, Xk, Xv);
  wtrans<<<dim3(16, 16, 4), 256, 0, stream>>>(Wq, Wk, Wv, Wo, Wqt, Wkt, Wvt, Wot);

  dim3 gg(EMBED / 128, MROWS / 128);  // (8, 32)
  gemm_bt<0><<<gg, 256, 0, stream>>>(Xq, Wqt, bq, Qb, 0.125f);  // fold 1/sqrt(64)
  gemm_bt<0><<<gg, 256, 0, stream>>>(Xk, Wkt, bk, Kb, 1.0f);
  gemm_bt<2><<<gg, 256, 0, stream>>>(Xv, Wvt, bv, Vtb, 1.0f);   // writes V^T [BH][D][S]

  attn<<<dim3(SEQ / 64, 32), 256, 0, stream>>>(Qb, Kb, Vtb, AO);

  gemm_bt<1><<<gg, 256, 0, stream>>>(AO, Wot, bo, out, 1.0f);
}

// Round 4
// 202.601 us; speedup vs baseline: 1.7176x; 1.1001x over previous
//
#include <hip/hip_runtime.h>
#include <hip/hip_bf16.h>

// Problem: B=2, S=2048, E=1024, H=16, D=64. All inputs fp32, output fp32.
// Pipeline: cvt X->bf16 | transpose W->bf16 [N][K] | GEMM-Q/K -> [BH][S][D]
//           (Q pre-scaled by log2e/8), GEMM-V -> V^T [BH][D][S]
//           | flash attention (swapped QK^T, exp2 softmax, in-lane stats)
//           | GEMM -> out fp32 + bo.
// LDS tiles: T2 XOR swizzle byte ^= ((row&7)<<4) within 128B rows; staged via
// global_load_lds with inverse-swizzled global source (linear LDS dest).
// Attn staging: single-buffer, full __syncthreads() drains (round-3 dbuf with
// counted vmcnt + raw barriers produced 1e-2-level intermittent errors ->
// reverted; bisect round).

#define EMBED 1024
#define NHEAD 16
#define HDIM 64
#define SEQ 2048
#define MROWS 4096  // B*S

typedef __attribute__((ext_vector_type(8))) __bf16 bf16x8;
typedef __attribute__((ext_vector_type(4))) float f32x4;

__device__ __forceinline__ unsigned short f2bf(float f) {
  unsigned int u = __builtin_bit_cast(unsigned int, f);
  u += 0x7fffu + ((u >> 16) & 1u);  // round-to-nearest-even
  return (unsigned short)(u >> 16);
}

// swizzled byte offset within a [rows][128B] LDS tile
__device__ __forceinline__ int swz(int row, int bcol) {
  return row * 128 + (bcol ^ ((row & 7) << 4));
}

// async global->LDS, 16B per lane. LDS dest = base + lane*16 (linear).
__device__ __forceinline__ void gload16(const void* g, void* l) {
  __builtin_amdgcn_global_load_lds((const __attribute__((address_space(1))) void*)g,
                                   (__attribute__((address_space(3))) void*)l, 16, 0, 0);
}

// ---- fp32 -> bf16, 8 elements/thread; blockIdx.y selects src/dst ----
__global__ __launch_bounds__(256) void cvt_f32_bf16(const float* __restrict__ i0, const float* __restrict__ i1,
                                                    const float* __restrict__ i2,
                                                    unsigned short* __restrict__ o0, unsigned short* __restrict__ o1,
                                                    unsigned short* __restrict__ o2) {
  const float* in; unsigned short* out;
  switch (blockIdx.y) {
    case 0: in = i0; out = o0; break;
    case 1: in = i1; out = o1; break;
    default: in = i2; out = o2; break;
  }
  int i = blockIdx.x * 256 + threadIdx.x;
  const float4* p = reinterpret_cast<const float4*>(in) + (size_t)i * 2;
  float4 a = p[0], b = p[1];
  int4 r;
  r.x = (int)f2bf(a.x) | ((int)f2bf(a.y) << 16);
  r.y = (int)f2bf(a.z) | ((int)f2bf(a.w) << 16);
  r.z = (int)f2bf(b.x) | ((int)f2bf(b.y) << 16);
  r.w = (int)f2bf(b.z) | ((int)f2bf(b.w) << 16);
  reinterpret_cast<int4*>(out)[i] = r;
}

// ---- W [K][N] fp32 -> Wt [N][K] bf16, 64x64 LDS tiles ----
__global__ __launch_bounds__(256) void wtrans(const float* __restrict__ w0, const float* __restrict__ w1,
                                              const float* __restrict__ w2, const float* __restrict__ w3,
                                              unsigned short* __restrict__ o0, unsigned short* __restrict__ o1,
                                              unsigned short* __restrict__ o2, unsigned short* __restrict__ o3) {
  __shared__ float tile[64][65];
  const float* src; unsigned short* dst;
  switch (blockIdx.z) {
    case 0: src = w0; dst = o0; break;
    case 1: src = w1; dst = o1; break;
    case 2: src = w2; dst = o2; break;
    default: src = w3; dst = o3; break;
  }
  const int k0 = blockIdx.y * 64, n0 = blockIdx.x * 64;
  const int c = threadIdx.x & 63, r0 = threadIdx.x >> 6;
#pragma unroll
  for (int i = 0; i < 16; ++i) {
    int r = r0 + i * 4;
    tile[r][c] = src[(size_t)(k0 + r) * EMBED + n0 + c];
  }
  __syncthreads();
#pragma unroll
  for (int i = 0; i < 16; ++i) {
    int nr = r0 + i * 4;
    dst[(size_t)(n0 + nr) * EMBED + k0 + c] = f2bf(tile[c][nr]);
  }
}

// ---- GEMM: C[4096x1024] = A @ Bt^T + bias, then *oscale ----
// A bf16 [M][K]; Bt bf16 [N][K]. Staging via global_load_lds (m97 pattern).
// MODE 0: bf16 scatter to [B*H][S][D]; MODE 1: fp32 row-major;
// MODE 2: bf16 V^T scatter to [B*H][D][S], 4 s-packed per 8B store.
template <int MODE>
__global__ __launch_bounds__(256) void gemm_bt(const unsigned short* __restrict__ A,
                                               const unsigned short* __restrict__ Bt,
                                               const float* __restrict__ bias,
                                               void* __restrict__ C, float oscale) {
  constexpr int K = EMBED;
  __shared__ __align__(16) unsigned short Alds[128 * 64];
  __shared__ __align__(16) unsigned short Blds[128 * 64];
  char* Ab8 = (char*)Alds; char* Bb8 = (char*)Blds;
  const char* AB = (const char*)A;
  const char* BB = (const char*)Bt;
  const int tid = threadIdx.x;
  const int lane = tid & 63, w = tid >> 6;
  const int wr = w >> 1, wc = w & 1;
  const int fr = lane & 15, fq = lane >> 4;
  const int m0 = blockIdx.y * 128, n0 = blockIdx.x * 128;
  const int bcol = (lane & 7) * 16;

  f32x4 acc[4][4];
#pragma unroll
  for (int m = 0; m < 4; ++m)
#pragma unroll
    for (int n = 0; n < 4; ++n) acc[m][n] = f32x4{0.f, 0.f, 0.f, 0.f};

  for (int k0 = 0; k0 < K; k0 += 64) {
    __syncthreads();
#pragma unroll
    for (int i = 0; i < 4; ++i) {
      int row = w * 32 + i * 8 + (lane >> 3);
      int sc_ = bcol ^ ((row & 7) << 4);
      gload16(AB + (size_t)(m0 + row) * (K * 2) + k0 * 2 + sc_, Ab8 + w * 4096 + i * 1024);
      gload16(BB + (size_t)(n0 + row) * (K * 2) + k0 * 2 + sc_, Bb8 + w * 4096 + i * 1024);
    }
    __syncthreads();  // drains vmcnt(0) -> tile staged
#pragma unroll
    for (int ks = 0; ks < 2; ++ks) {
      bf16x8 af[4], bfr[4];
#pragma unroll
      for (int m = 0; m < 4; ++m) {
        int ar = wr * 64 + m * 16 + fr;
        af[m] = *reinterpret_cast<const bf16x8*>(Ab8 + swz(ar, ks * 64 + fq * 16));
      }
#pragma unroll
      for (int n = 0; n < 4; ++n) {
        int br = wc * 64 + n * 16 + fr;
        bfr[n] = *reinterpret_cast<const bf16x8*>(Bb8 + swz(br, ks * 64 + fq * 16));
      }
#pragma unroll
      for (int m = 0; m < 4; ++m)
#pragma unroll
        for (int n = 0; n < 4; ++n)
          acc[m][n] = __builtin_amdgcn_mfma_f32_16x16x32_bf16(af[m], bfr[n], acc[m][n], 0, 0, 0);
    }
  }

#pragma unroll
  for (int n = 0; n < 4; ++n) {
    int col = n0 + wc * 64 + n * 16 + fr;
    float bv = bias[col];
#pragma unroll
    for (int m = 0; m < 4; ++m) {
      int rowb = m0 + wr * 64 + m * 16 + fq * 4;
      if constexpr (MODE == 2) {
        int b = rowb >> 11, s0 = rowb & (SEQ - 1);
        int h = col >> 6, d = col & 63;
        int2 pk;
        unsigned short e0 = f2bf((acc[m][n][0] + bv) * oscale);
        unsigned short e1 = f2bf((acc[m][n][1] + bv) * oscale);
        unsigned short e2 = f2bf((acc[m][n][2] + bv) * oscale);
        unsigned short e3 = f2bf((acc[m][n][3] + bv) * oscale);
        pk.x = (int)e0 | ((int)e1 << 16);
        pk.y = (int)e2 | ((int)e3 << 16);
        *reinterpret_cast<int2*>(
            &reinterpret_cast<unsigned short*>(C)[((size_t)((b * NHEAD + h) * HDIM + d)) * SEQ + s0]) = pk;
      } else {
#pragma unroll
        for (int r = 0; r < 4; ++r) {
          int row = rowb + r;
          float v = (acc[m][n][r] + bv) * oscale;
          if constexpr (MODE == 0) {
            int b = row >> 11, s = row & (SEQ - 1), h = col >> 6, d = col & 63;
            reinterpret_cast<unsigned short*>(C)[((size_t)((b * NHEAD + h) * SEQ + s) << 6) + d] = f2bf(v);
          } else {
            reinterpret_cast<float*>(C)[(size_t)row * EMBED + col] = v;
          }
        }
      }
    }
  }
}

// ---- flash attention ----
// Q,K bf16 [B*H][S][D] (Q pre-scaled by log2e/8); Vt bf16 [B*H][D][S].
// Swapped QK^T: sc = mfma(K,Q) -> S^T, all 64 k-scores for q=fr in-lane.
// Single-buffer K/V staging via global_load_lds, full __syncthreads drains.
__global__ __launch_bounds__(256) void attn(const unsigned short* __restrict__ Q,
                                            const unsigned short* __restrict__ Kk,
                                            const unsigned short* __restrict__ Vt,
                                            unsigned short* __restrict__ AO) {
  __shared__ __align__(16) unsigned short Klds[64 * 64];
  __shared__ __align__(16) unsigned short Vlds[64 * 64];  // [d][k]
  __shared__ __align__(16) unsigned short Plds[4][16 * 64];
  char* Kb8 = (char*)Klds;
  char* Vb8 = (char*)Vlds;
  const int tid = threadIdx.x, lane = tid & 63, w = tid >> 6;
  const int fr = lane & 15, fq = lane >> 4;
  char* Pb8 = (char*)&Plds[w][0];

  // XCD swizzle: all 32 q-blocks of a head on one XCD (round-robin lin%8).
  const int lin = blockIdx.x;
  const int head = (lin & 7) * 4 + ((lin >> 3) & 3);
  const int q0 = (lin >> 5) * 64;
  const size_t hb = (size_t)head * SEQ * HDIM;
  const unsigned short* Qh = Q + hb;
  const char* KhB = (const char*)(Kk + hb);
  const char* VhB = (const char*)(Vt + hb);  // rows d, 4096B each

  const int bcol = (lane & 7) * 16;

  bf16x8 qf[2];
  {
    size_t qoff = (size_t)(q0 + w * 16 + fr) * HDIM + fq * 8;
    qf[0] = *reinterpret_cast<const bf16x8*>(&Qh[qoff]);
    qf[1] = *reinterpret_cast<const bf16x8*>(&Qh[qoff + 32]);
  }
  f32x4 oacc[4];
#pragma unroll
  for (int n = 0; n < 4; ++n) oacc[n] = f32x4{0.f, 0.f, 0.f, 0.f};
  float mrow = -1e30f, lrow = 0.f;
  const int rsrc = (fq << 4) + (fq << 2);  // lane fq*16 + fq*4 (+rr): stats for q=fq*4+rr

  for (int kt = 0; kt < SEQ / 64; ++kt) {
    __syncthreads();  // prior tile's reads complete before overwrite
#pragma unroll
    for (int i = 0; i < 2; ++i) {
      int row = w * 16 + i * 8 + (lane >> 3);
      int sc_ = bcol ^ ((row & 7) << 4);
      gload16(KhB + (size_t)(kt * 64 + row) * 128 + sc_, Kb8 + w * 2048 + i * 1024);
      gload16(VhB + (size_t)row * (SEQ * 2) + kt * 128 + sc_, Vb8 + w * 2048 + i * 1024);
    }
    __syncthreads();  // drains vmcnt(0) -> tile staged

    // S^T = K·Q^T: sc[n] rows k = n*16+fq*4+r, col q = fr (log2 domain)
    f32x4 sc[4];
#pragma unroll
    for (int n = 0; n < 4; ++n) {
      int kr = n * 16 + fr;
      bf16x8 k0 = *reinterpret_cast<const bf16x8*>(Kb8 + swz(kr, fq * 16));
      bf16x8 k1 = *reinterpret_cast<const bf16x8*>(Kb8 + swz(kr, 64 + fq * 16));
      f32x4 a = f32x4{0.f, 0.f, 0.f, 0.f};
      a = __builtin_amdgcn_mfma_f32_16x16x32_bf16(k0, qf[0], a, 0, 0, 0);
      a = __builtin_amdgcn_mfma_f32_16x16x32_bf16(k1, qf[1], a, 0, 0, 0);
      sc[n] = a;
    }

    // in-lane softmax over the 16 scores (all for q=fr)
    float mx[4];
#pragma unroll
    for (int n = 0; n < 4; ++n)
      mx[n] = fmaxf(fmaxf(sc[n][0], sc[n][1]), fmaxf(sc[n][2], sc[n][3]));
    float mt = fmaxf(fmaxf(mx[0], mx[1]), fmaxf(mx[2], mx[3]));
    mt = fmaxf(mt, __shfl_xor(mt, 16));
    mt = fmaxf(mt, __shfl_xor(mt, 32));
    float mn = fmaxf(mrow, mt);
    float resc = exp2f(mrow - mn);
    float p[4][4];
    float ps = 0.f;
#pragma unroll
    for (int n = 0; n < 4; ++n)
#pragma unroll
      for (int r = 0; r < 4; ++r) {
        p[n][r] = exp2f(sc[n][r] - mn);
        ps += p[n][r];
      }
    ps += __shfl_xor(ps, 16);
    ps += __shfl_xor(ps, 32);
    lrow = lrow * resc + ps;
    mrow = mn;

    // redistribute resc to oacc rows q = fq*4+rr, rescale O
    float rq[4];
#pragma unroll
    for (int rr = 0; rr < 4; ++rr) rq[rr] = __shfl(resc, rsrc + rr, 64);
#pragma unroll
    for (int n = 0; n < 4; ++n)
#pragma unroll
      for (int rr = 0; rr < 4; ++rr) oacc[n][rr] *= rq[rr];

    // P -> Plds[q=fr][k] (swizzled), 4x ds_write_b64; k = n*16+fq*4+r
#pragma unroll
    for (int n = 0; n < 4; ++n) {
      int2 pk;
      pk.x = (int)f2bf(p[n][0]) | ((int)f2bf(p[n][1]) << 16);
      pk.y = (int)f2bf(p[n][2]) | ((int)f2bf(p[n][3]) << 16);
      *reinterpret_cast<int2*>(Pb8 + swz(fr, n * 32 + fq * 8)) = pk;
    }

    bf16x8 pa0 = *reinterpret_cast<const bf16x8*>(Pb8 + swz(fr, fq * 16));
    bf16x8 pa1 = *reinterpret_cast<const bf16x8*>(Pb8 + swz(fr, 64 + fq * 16));
#pragma unroll
    for (int n = 0; n < 4; ++n) {
      int dr = n * 16 + fr;
      bf16x8 vb0 = *reinterpret_cast<const bf16x8*>(Vb8 + swz(dr, fq * 16));
      bf16x8 vb1 = *reinterpret_cast<const bf16x8*>(Vb8 + swz(dr, 64 + fq * 16));
      oacc[n] = __builtin_amdgcn_mfma_f32_16x16x32_bf16(pa0, vb0, oacc[n], 0, 0, 0);
      oacc[n] = __builtin_amdgcn_mfma_f32_16x16x32_bf16(pa1, vb1, oacc[n], 0, 0, 0);
    }
  }

  const int b = head >> 4, h = head & 15;
  float lr[4];
#pragma unroll
  for (int rr = 0; rr < 4; ++rr) lr[rr] = __shfl(lrow, rsrc + rr, 64);
#pragma unroll
  for (int rr = 0; rr < 4; ++rr) {
    float inv = 1.0f / lr[rr];
    int srow = q0 + w * 16 + fq * 4 + rr;
    size_t ob = (size_t)(b * SEQ + srow) * EMBED + h * 64;
#pragma unroll
    for (int n = 0; n < 4; ++n) AO[ob + n * 16 + fr] = f2bf(oacc[n][rr] * inv);
  }
}

extern "C" void kernel_launch(void* const* d_in, const int* in_sizes, int n_in,
                              void* d_out, int out_size, void* d_ws, size_t ws_size,
                              hipStream_t stream) {
  const float* q32 = (const float*)d_in[0];
  const float* k32 = (const float*)d_in[1];
  const float* v32 = (const float*)d_in[2];
  const float* Wq = (const float*)d_in[3]; const float* bq = (const float*)d_in[4];
  const float* Wk = (const float*)d_in[5]; const float* bk = (const float*)d_in[6];
  const float* Wv = (const float*)d_in[7]; const float* bv = (const float*)d_in[8];
  const float* Wo = (const float*)d_in[9]; const float* bo = (const float*)d_in[10];
  float* out = (float*)d_out;

  char* ws = (char*)d_ws;
  const size_t MB = 1u << 20;
  unsigned short* Xq  = (unsigned short*)(ws + 0 * MB);
  unsigned short* Xk  = (unsigned short*)(ws + 8 * MB);
  unsigned short* Xv  = (unsigned short*)(ws + 16 * MB);
  unsigned short* Wqt = (unsigned short*)(ws + 24 * MB);
  unsigned short* Wkt = (unsigned short*)(ws + 26 * MB);
  unsigned short* Wvt = (unsigned short*)(ws + 28 * MB);
  unsigned short* Wot = (unsigned short*)(ws + 30 * MB);
  unsigned short* Qb  = (unsigned short*)(ws + 32 * MB);
  unsigned short* Kb  = (unsigned short*)(ws + 40 * MB);
  unsigned short* Vtb = (unsigned short*)(ws + 48 * MB);
  unsigned short* AO  = Xq;  // safe: GEMM-Q (sole Xq reader) completes before attn writes

  const int n8 = (MROWS * EMBED) / 8;  // 524288
  cvt_f32_bf16<<<dim3(n8 / 256, 3), 256, 0, stream>>>(q32, k32, v32, Xq, Xk, Xv);
  wtrans<<<dim3(16, 16, 4), 256, 0, stream>>>(Wq, Wk, Wv, Wo, Wqt, Wkt, Wvt, Wot);

  dim3 gg(EMBED / 128, MROWS / 128);  // (8, 32)
  const float qscale = 0.125f * 1.44269504088896340736f;  // (1/sqrt(64)) * log2(e)
  gemm_bt<0><<<gg, 256, 0, stream>>>(Xq, Wqt, bq, Qb, qscale);
  gemm_bt<0><<<gg, 256, 0, stream>>>(Xk, Wkt, bk, Kb, 1.0f);
  gemm_bt<2><<<gg, 256, 0, stream>>>(Xv, Wvt, bv, Vtb, 1.0f);  // V^T [BH][D][S]

  attn<<<dim3(SEQ / 64 * 32), 256, 0, stream>>>(Qb, Kb, Vtb, AO);

  gemm_bt<1><<<gg, 256, 0, stream>>>(AO, Wot, bo, out, 1.0f);
}

// Round 5
// 167.283 us; speedup vs baseline: 2.0802x; 1.2111x over previous
//
#include <hip/hip_runtime.h>
#include <hip/hip_bf16.h>

// Problem: B=2, S=2048, E=1024, H=16, D=64. All inputs fp32, output fp32.
// Pipeline: cvt X->bf16 | transpose W->bf16 [N][K] | fused QKV GEMM (grid.z=3,
//           3 blocks/CU) -> Q(scaled log2e/8),K [BH][S][D], V^T [BH][D][S]
//           | flash attention (swapped QK^T, exp2 softmax, defer-max T13,
//           cvt_pk T12, single-buffer full-drain staging) | GEMM -> fp32 + bo.
// LDS tiles: T2 XOR swizzle byte ^= ((row&7)<<4) within 128B rows; staged via
// global_load_lds with inverse-swizzled global source (linear LDS dest).
// NOTE round-3 post-mortem: dbuf + counted vmcnt + raw barriers raced (1e-2
// errors) -> attn keeps full __syncthreads() drains (verified template).

#define EMBED 1024
#define NHEAD 16
#define HDIM 64
#define SEQ 2048
#define MROWS 4096  // B*S

typedef __attribute__((ext_vector_type(8))) __bf16 bf16x8;
typedef __attribute__((ext_vector_type(4))) float f32x4;

__device__ __forceinline__ unsigned short f2bf(float f) {
  unsigned int u = __builtin_bit_cast(unsigned int, f);
  u += 0x7fffu + ((u >> 16) & 1u);  // round-to-nearest-even
  return (unsigned short)(u >> 16);
}

// packed f32x2 -> bf16x2 (T12 recipe; no builtin on gfx950)
__device__ __forceinline__ int cvtpk_bf16(float lo, float hi) {
  int r;
  asm("v_cvt_pk_bf16_f32 %0, %1, %2" : "=v"(r) : "v"(lo), "v"(hi));
  return r;
}

// swizzled byte offset within a [rows][128B] LDS tile
__device__ __forceinline__ int swz(int row, int bcol) {
  return row * 128 + (bcol ^ ((row & 7) << 4));
}

// async global->LDS, 16B per lane. LDS dest = base + lane*16 (linear).
__device__ __forceinline__ void gload16(const void* g, void* l) {
  __builtin_amdgcn_global_load_lds((const __attribute__((address_space(1))) void*)g,
                                   (__attribute__((address_space(3))) void*)l, 16, 0, 0);
}

// ---- fp32 -> bf16, 8 elements/thread; blockIdx.y selects src/dst ----
__global__ __launch_bounds__(256) void cvt_f32_bf16(const float* __restrict__ i0, const float* __restrict__ i1,
                                                    const float* __restrict__ i2,
                                                    unsigned short* __restrict__ o0, unsigned short* __restrict__ o1,
                                                    unsigned short* __restrict__ o2) {
  const float* in; unsigned short* out;
  switch (blockIdx.y) {
    case 0: in = i0; out = o0; break;
    case 1: in = i1; out = o1; break;
    default: in = i2; out = o2; break;
  }
  int i = blockIdx.x * 256 + threadIdx.x;
  const float4* p = reinterpret_cast<const float4*>(in) + (size_t)i * 2;
  float4 a = p[0], b = p[1];
  int4 r;
  r.x = cvtpk_bf16(a.x, a.y);
  r.y = cvtpk_bf16(a.z, a.w);
  r.z = cvtpk_bf16(b.x, b.y);
  r.w = cvtpk_bf16(b.z, b.w);
  reinterpret_cast<int4*>(out)[i] = r;
}

// ---- W [K][N] fp32 -> Wt [N][K] bf16, 64x64 LDS tiles ----
__global__ __launch_bounds__(256) void wtrans(const float* __restrict__ w0, const float* __restrict__ w1,
                                              const float* __restrict__ w2, const float* __restrict__ w3,
                                              unsigned short* __restrict__ o0, unsigned short* __restrict__ o1,
                                              unsigned short* __restrict__ o2, unsigned short* __restrict__ o3) {
  __shared__ float tile[64][65];
  const float* src; unsigned short* dst;
  switch (blockIdx.z) {
    case 0: src = w0; dst = o0; break;
    case 1: src = w1; dst = o1; break;
    case 2: src = w2; dst = o2; break;
    default: src = w3; dst = o3; break;
  }
  const int k0 = blockIdx.y * 64, n0 = blockIdx.x * 64;
  const int c = threadIdx.x & 63, r0 = threadIdx.x >> 6;
#pragma unroll
  for (int i = 0; i < 16; ++i) {
    int r = r0 + i * 4;
    tile[r][c] = src[(size_t)(k0 + r) * EMBED + n0 + c];
  }
  __syncthreads();
#pragma unroll
  for (int i = 0; i < 16; ++i) {
    int nr = r0 + i * 4;
    dst[(size_t)(n0 + nr) * EMBED + k0 + c] = f2bf(tile[c][nr]);
  }
}

// ---- shared GEMM core: C[128x128 tile] = A @ Bt^T + bias, then *oscale ----
// A bf16 [M][K]; Bt bf16 [N][K]. Staging via global_load_lds (m97 pattern).
// mode 0: bf16 scatter to [B*H][S][D]; mode 1: fp32 row-major;
// mode 2: bf16 V^T scatter to [B*H][D][S], 4 s-packed per 8B store.
__device__ __forceinline__ void gemm_core(const unsigned short* __restrict__ A,
                                          const unsigned short* __restrict__ Bt,
                                          const float* __restrict__ bias,
                                          void* __restrict__ C, float oscale, int mode) {
  constexpr int K = EMBED;
  __shared__ __align__(16) unsigned short Alds[128 * 64];
  __shared__ __align__(16) unsigned short Blds[128 * 64];
  char* Ab8 = (char*)Alds; char* Bb8 = (char*)Blds;
  const char* AB = (const char*)A;
  const char* BB = (const char*)Bt;
  const int tid = threadIdx.x;
  const int lane = tid & 63, w = tid >> 6;
  const int wr = w >> 1, wc = w & 1;
  const int fr = lane & 15, fq = lane >> 4;
  const int m0 = blockIdx.y * 128, n0 = blockIdx.x * 128;
  const int bcol = (lane & 7) * 16;

  f32x4 acc[4][4];
#pragma unroll
  for (int m = 0; m < 4; ++m)
#pragma unroll
    for (int n = 0; n < 4; ++n) acc[m][n] = f32x4{0.f, 0.f, 0.f, 0.f};

  for (int k0 = 0; k0 < K; k0 += 64) {
    __syncthreads();
#pragma unroll
    for (int i = 0; i < 4; ++i) {
      int row = w * 32 + i * 8 + (lane >> 3);
      int sc_ = bcol ^ ((row & 7) << 4);
      gload16(AB + (size_t)(m0 + row) * (K * 2) + k0 * 2 + sc_, Ab8 + w * 4096 + i * 1024);
      gload16(BB + (size_t)(n0 + row) * (K * 2) + k0 * 2 + sc_, Bb8 + w * 4096 + i * 1024);
    }
    __syncthreads();  // drains vmcnt(0) -> tile staged
#pragma unroll
    for (int ks = 0; ks < 2; ++ks) {
      bf16x8 af[4], bfr[4];
#pragma unroll
      for (int m = 0; m < 4; ++m) {
        int ar = wr * 64 + m * 16 + fr;
        af[m] = *reinterpret_cast<const bf16x8*>(Ab8 + swz(ar, ks * 64 + fq * 16));
      }
#pragma unroll
      for (int n = 0; n < 4; ++n) {
        int br = wc * 64 + n * 16 + fr;
        bfr[n] = *reinterpret_cast<const bf16x8*>(Bb8 + swz(br, ks * 64 + fq * 16));
      }
#pragma unroll
      for (int m = 0; m < 4; ++m)
#pragma unroll
        for (int n = 0; n < 4; ++n)
          acc[m][n] = __builtin_amdgcn_mfma_f32_16x16x32_bf16(af[m], bfr[n], acc[m][n], 0, 0, 0);
    }
  }

#pragma unroll
  for (int n = 0; n < 4; ++n) {
    int col = n0 + wc * 64 + n * 16 + fr;
    float bv = bias[col];
#pragma unroll
    for (int m = 0; m < 4; ++m) {
      int rowb = m0 + wr * 64 + m * 16 + fq * 4;
      if (mode == 2) {
        int b = rowb >> 11, s0 = rowb & (SEQ - 1);
        int h = col >> 6, d = col & 63;
        int2 pk;
        pk.x = cvtpk_bf16((acc[m][n][0] + bv) * oscale, (acc[m][n][1] + bv) * oscale);
        pk.y = cvtpk_bf16((acc[m][n][2] + bv) * oscale, (acc[m][n][3] + bv) * oscale);
        *reinterpret_cast<int2*>(
            &reinterpret_cast<unsigned short*>(C)[((size_t)((b * NHEAD + h) * HDIM + d)) * SEQ + s0]) = pk;
      } else if (mode == 0) {
#pragma unroll
        for (int r = 0; r < 4; ++r) {
          int row = rowb + r;
          float v = (acc[m][n][r] + bv) * oscale;
          int b = row >> 11, s = row & (SEQ - 1), h = col >> 6, d = col & 63;
          reinterpret_cast<unsigned short*>(C)[((size_t)((b * NHEAD + h) * SEQ + s) << 6) + d] = f2bf(v);
        }
      } else {
#pragma unroll
        for (int r = 0; r < 4; ++r)
          reinterpret_cast<float*>(C)[(size_t)(rowb + r) * EMBED + col] = acc[m][n][r] + bv;
      }
    }
  }
}

// fused QKV projection: blockIdx.z picks {Q, K, V}; 768 blocks = 3/CU.
__global__ __launch_bounds__(256) void gemm_qkv(
    const unsigned short* __restrict__ Xq, const unsigned short* __restrict__ Xk,
    const unsigned short* __restrict__ Xv,
    const unsigned short* __restrict__ Wqt, const unsigned short* __restrict__ Wkt,
    const unsigned short* __restrict__ Wvt,
    const float* __restrict__ bq, const float* __restrict__ bk, const float* __restrict__ bv,
    unsigned short* __restrict__ Qb, unsigned short* __restrict__ Kb,
    unsigned short* __restrict__ Vtb, float qscale) {
  switch (blockIdx.z) {
    case 0: gemm_core(Xq, Wqt, bq, Qb, qscale, 0); break;
    case 1: gemm_core(Xk, Wkt, bk, Kb, 1.0f, 0); break;
    default: gemm_core(Xv, Wvt, bv, Vtb, 1.0f, 2); break;
  }
}

__global__ __launch_bounds__(256) void gemm_out(const unsigned short* __restrict__ A,
                                                const unsigned short* __restrict__ Bt,
                                                const float* __restrict__ bias,
                                                float* __restrict__ C) {
  gemm_core(A, Bt, bias, C, 1.0f, 1);
}

// ---- flash attention ----
// Q,K bf16 [B*H][S][D] (Q pre-scaled by log2e/8); Vt bf16 [B*H][D][S].
// Swapped QK^T: sc = mfma(K,Q) -> S^T, all 64 k-scores for q=fr in-lane.
// Single-buffer K/V staging via global_load_lds, full __syncthreads drains.
// Defer-max: skip O-rescale while tile max stays within 2^8 of running max.
__global__ __launch_bounds__(256) void attn(const unsigned short* __restrict__ Q,
                                            const unsigned short* __restrict__ Kk,
                                            const unsigned short* __restrict__ Vt,
                                            unsigned short* __restrict__ AO) {
  __shared__ __align__(16) unsigned short Klds[64 * 64];
  __shared__ __align__(16) unsigned short Vlds[64 * 64];  // [d][k]
  __shared__ __align__(16) unsigned short Plds[4][16 * 64];
  char* Kb8 = (char*)Klds;
  char* Vb8 = (char*)Vlds;
  const int tid = threadIdx.x, lane = tid & 63, w = tid >> 6;
  const int fr = lane & 15, fq = lane >> 4;
  char* Pb8 = (char*)&Plds[w][0];

  // XCD swizzle: all 32 q-blocks of a head on one XCD (round-robin lin%8).
  const int lin = blockIdx.x;
  const int head = (lin & 7) * 4 + ((lin >> 3) & 3);
  const int q0 = (lin >> 5) * 64;
  const size_t hb = (size_t)head * SEQ * HDIM;
  const unsigned short* Qh = Q + hb;
  const char* KhB = (const char*)(Kk + hb);
  const char* VhB = (const char*)(Vt + hb);  // rows d, 4096B each

  const int bcol = (lane & 7) * 16;

  bf16x8 qf[2];
  {
    size_t qoff = (size_t)(q0 + w * 16 + fr) * HDIM + fq * 8;
    qf[0] = *reinterpret_cast<const bf16x8*>(&Qh[qoff]);
    qf[1] = *reinterpret_cast<const bf16x8*>(&Qh[qoff + 32]);
  }
  f32x4 oacc[4];
#pragma unroll
  for (int n = 0; n < 4; ++n) oacc[n] = f32x4{0.f, 0.f, 0.f, 0.f};
  float mrow = -1e30f, lrow = 0.f;
  const int rsrc = (fq << 4) + (fq << 2);  // lane fq*16 + fq*4 (+rr): stats for q=fq*4+rr

  for (int kt = 0; kt < SEQ / 64; ++kt) {
    __syncthreads();  // prior tile's reads complete before overwrite
#pragma unroll
    for (int i = 0; i < 2; ++i) {
      int row = w * 16 + i * 8 + (lane >> 3);
      int sc_ = bcol ^ ((row & 7) << 4);
      gload16(KhB + (size_t)(kt * 64 + row) * 128 + sc_, Kb8 + w * 2048 + i * 1024);
      gload16(VhB + (size_t)row * (SEQ * 2) + kt * 128 + sc_, Vb8 + w * 2048 + i * 1024);
    }
    __syncthreads();  // drains vmcnt(0) -> tile staged

    // S^T = K·Q^T: sc[n] rows k = n*16+fq*4+r, col q = fr (log2 domain)
    f32x4 sc[4];
#pragma unroll
    for (int n = 0; n < 4; ++n) {
      int kr = n * 16 + fr;
      bf16x8 k0 = *reinterpret_cast<const bf16x8*>(Kb8 + swz(kr, fq * 16));
      bf16x8 k1 = *reinterpret_cast<const bf16x8*>(Kb8 + swz(kr, 64 + fq * 16));
      f32x4 a = f32x4{0.f, 0.f, 0.f, 0.f};
      a = __builtin_amdgcn_mfma_f32_16x16x32_bf16(k0, qf[0], a, 0, 0, 0);
      a = __builtin_amdgcn_mfma_f32_16x16x32_bf16(k1, qf[1], a, 0, 0, 0);
      sc[n] = a;
    }

    // tile max for this lane's q (=fr): 16 in-lane + 2 cross-lane
    float mx0 = fmaxf(fmaxf(sc[0][0], sc[0][1]), fmaxf(sc[0][2], sc[0][3]));
    float mx1 = fmaxf(fmaxf(sc[1][0], sc[1][1]), fmaxf(sc[1][2], sc[1][3]));
    float mx2 = fmaxf(fmaxf(sc[2][0], sc[2][1]), fmaxf(sc[2][2], sc[2][3]));
    float mx3 = fmaxf(fmaxf(sc[3][0], sc[3][1]), fmaxf(sc[3][2], sc[3][3]));
    float mt = fmaxf(fmaxf(mx0, mx1), fmaxf(mx2, mx3));
    mt = fmaxf(mt, __shfl_xor(mt, 16));
    mt = fmaxf(mt, __shfl_xor(mt, 32));

    // T13 defer-max: only rescale when some row's max grew past 2^8 headroom
    if (!__all(mt <= mrow + 8.0f)) {
      float mn = fmaxf(mrow, mt);
      float resc = exp2f(mrow - mn);
      lrow *= resc;
      float rq[4];
#pragma unroll
      for (int rr = 0; rr < 4; ++rr) rq[rr] = __shfl(resc, rsrc + rr, 64);
#pragma unroll
      for (int n = 0; n < 4; ++n)
#pragma unroll
        for (int rr = 0; rr < 4; ++rr) oacc[n][rr] *= rq[rr];
      mrow = mn;
    }

    float p[4][4];
    float ps = 0.f;
#pragma unroll
    for (int n = 0; n < 4; ++n)
#pragma unroll
      for (int r = 0; r < 4; ++r) {
        p[n][r] = exp2f(sc[n][r] - mrow);
        ps += p[n][r];
      }
    ps += __shfl_xor(ps, 16);
    ps += __shfl_xor(ps, 32);
    lrow += ps;

    // P -> Plds[q=fr][k] (swizzled), 4x ds_write_b64 via cvt_pk; k = n*16+fq*4+r
#pragma unroll
    for (int n = 0; n < 4; ++n) {
      int2 pk;
      pk.x = cvtpk_bf16(p[n][0], p[n][1]);
      pk.y = cvtpk_bf16(p[n][2], p[n][3]);
      *reinterpret_cast<int2*>(Pb8 + swz(fr, n * 32 + fq * 8)) = pk;
    }

    bf16x8 pa0 = *reinterpret_cast<const bf16x8*>(Pb8 + swz(fr, fq * 16));
    bf16x8 pa1 = *reinterpret_cast<const bf16x8*>(Pb8 + swz(fr, 64 + fq * 16));
#pragma unroll
    for (int n = 0; n < 4; ++n) {
      int dr = n * 16 + fr;
      bf16x8 vb0 = *reinterpret_cast<const bf16x8*>(Vb8 + swz(dr, fq * 16));
      bf16x8 vb1 = *reinterpret_cast<const bf16x8*>(Vb8 + swz(dr, 64 + fq * 16));
      oacc[n] = __builtin_amdgcn_mfma_f32_16x16x32_bf16(pa0, vb0, oacc[n], 0, 0, 0);
      oacc[n] = __builtin_amdgcn_mfma_f32_16x16x32_bf16(pa1, vb1, oacc[n], 0, 0, 0);
    }
  }

  const int b = head >> 4, h = head & 15;
  float lr[4];
#pragma unroll
  for (int rr = 0; rr < 4; ++rr) lr[rr] = __shfl(lrow, rsrc + rr, 64);
#pragma unroll
  for (int rr = 0; rr < 4; ++rr) {
    float inv = 1.0f / lr[rr];
    int srow = q0 + w * 16 + fq * 4 + rr;
    size_t ob = (size_t)(b * SEQ + srow) * EMBED + h * 64;
#pragma unroll
    for (int n = 0; n < 4; ++n) AO[ob + n * 16 + fr] = f2bf(oacc[n][rr] * inv);
  }
}

extern "C" void kernel_launch(void* const* d_in, const int* in_sizes, int n_in,
                              void* d_out, int out_size, void* d_ws, size_t ws_size,
                              hipStream_t stream) {
  const float* q32 = (const float*)d_in[0];
  const float* k32 = (const float*)d_in[1];
  const float* v32 = (const float*)d_in[2];
  const float* Wq = (const float*)d_in[3]; const float* bq = (const float*)d_in[4];
  const float* Wk = (const float*)d_in[5]; const float* bk = (const float*)d_in[6];
  const float* Wv = (const float*)d_in[7]; const float* bv = (const float*)d_in[8];
  const float* Wo = (const float*)d_in[9]; const float* bo = (const float*)d_in[10];
  float* out = (float*)d_out;

  char* ws = (char*)d_ws;
  const size_t MB = 1u << 20;
  unsigned short* Xq  = (unsigned short*)(ws + 0 * MB);
  unsigned short* Xk  = (unsigned short*)(ws + 8 * MB);
  unsigned short* Xv  = (unsigned short*)(ws + 16 * MB);
  unsigned short* Wqt = (unsigned short*)(ws + 24 * MB);
  unsigned short* Wkt = (unsigned short*)(ws + 26 * MB);
  unsigned short* Wvt = (unsigned short*)(ws + 28 * MB);
  unsigned short* Wot = (unsigned short*)(ws + 30 * MB);
  unsigned short* Qb  = (unsigned short*)(ws + 32 * MB);
  unsigned short* Kb  = (unsigned short*)(ws + 40 * MB);
  unsigned short* Vtb = (unsigned short*)(ws + 48 * MB);
  unsigned short* AO  = Xq;  // safe: GEMM-Q (sole Xq reader) completes before attn writes

  const int n8 = (MROWS * EMBED) / 8;  // 524288
  cvt_f32_bf16<<<dim3(n8 / 256, 3), 256, 0, stream>>>(q32, k32, v32, Xq, Xk, Xv);
  wtrans<<<dim3(16, 16, 4), 256, 0, stream>>>(Wq, Wk, Wv, Wo, Wqt, Wkt, Wvt, Wot);

  const float qscale = 0.125f * 1.44269504088896340736f;  // (1/sqrt(64)) * log2(e)
  gemm_qkv<<<dim3(EMBED / 128, MROWS / 128, 3), 256, 0, stream>>>(
      Xq, Xk, Xv, Wqt, Wkt, Wvt, bq, bk, bv, Qb, Kb, Vtb, qscale);

  attn<<<dim3(SEQ / 64 * 32), 256, 0, stream>>>(Qb, Kb, Vtb, AO);

  gemm_out<<<dim3(EMBED / 128, MROWS / 128), 256, 0, stream>>>(AO, Wot, bo, out);
}

// Round 6
// 163.096 us; speedup vs baseline: 2.1336x; 1.0257x over previous
//
#include <hip/hip_runtime.h>
#include <hip/hip_bf16.h>

// Problem: B=2, S=2048, E=1024, H=16, D=64. All inputs fp32, output fp32.
// Pipeline: cvt X->bf16 | transpose W->bf16 [N][K] | fused QKV GEMM (grid.z=3,
//           3 blocks/CU) -> Q(scaled log2e/8),K [BH][S][D], V^T [BH][D][S]
//           | flash attention (swapped QK^T, exp2 softmax, defer-max T13,
//           cvt_pk T12, T14 reg-staged double-buffer: load->regs during
//           compute, ds_write after, ONE __syncthreads per tile; compiler
//           orders load->write via register dependency -- no manual vmcnt)
//           | GEMM -> fp32 + bo.
// LDS tiles: T2 XOR swizzle byte ^= ((row&7)<<4) within 128B rows; GEMMs stage
// via global_load_lds with inverse-swizzled global source (linear LDS dest);
// attn stages via regs with the same inverse-swizzled source + linear write.
// NOTE round-3 post-mortem: dbuf + counted vmcnt + raw barriers raced (1e-2
// errors) -> no manual waitcnt in attn; full __syncthreads() only.

#define EMBED 1024
#define NHEAD 16
#define HDIM 64
#define SEQ 2048
#define MROWS 4096  // B*S

typedef __attribute__((ext_vector_type(8))) __bf16 bf16x8;
typedef __attribute__((ext_vector_type(4))) float f32x4;

__device__ __forceinline__ unsigned short f2bf(float f) {
  unsigned int u = __builtin_bit_cast(unsigned int, f);
  u += 0x7fffu + ((u >> 16) & 1u);  // round-to-nearest-even
  return (unsigned short)(u >> 16);
}

// packed f32x2 -> bf16x2 (T12 recipe; no builtin on gfx950)
__device__ __forceinline__ int cvtpk_bf16(float lo, float hi) {
  int r;
  asm("v_cvt_pk_bf16_f32 %0, %1, %2" : "=v"(r) : "v"(lo), "v"(hi));
  return r;
}

// swizzled byte offset within a [rows][128B] LDS tile
__device__ __forceinline__ int swz(int row, int bcol) {
  return row * 128 + (bcol ^ ((row & 7) << 4));
}

// async global->LDS, 16B per lane. LDS dest = base + lane*16 (linear).
__device__ __forceinline__ void gload16(const void* g, void* l) {
  __builtin_amdgcn_global_load_lds((const __attribute__((address_space(1))) void*)g,
                                   (__attribute__((address_space(3))) void*)l, 16, 0, 0);
}

// ---- fp32 -> bf16, 8 elements/thread; blockIdx.y selects src/dst ----
__global__ __launch_bounds__(256) void cvt_f32_bf16(const float* __restrict__ i0, const float* __restrict__ i1,
                                                    const float* __restrict__ i2,
                                                    unsigned short* __restrict__ o0, unsigned short* __restrict__ o1,
                                                    unsigned short* __restrict__ o2) {
  const float* in; unsigned short* out;
  switch (blockIdx.y) {
    case 0: in = i0; out = o0; break;
    case 1: in = i1; out = o1; break;
    default: in = i2; out = o2; break;
  }
  int i = blockIdx.x * 256 + threadIdx.x;
  const float4* p = reinterpret_cast<const float4*>(in) + (size_t)i * 2;
  float4 a = p[0], b = p[1];
  int4 r;
  r.x = cvtpk_bf16(a.x, a.y);
  r.y = cvtpk_bf16(a.z, a.w);
  r.z = cvtpk_bf16(b.x, b.y);
  r.w = cvtpk_bf16(b.z, b.w);
  reinterpret_cast<int4*>(out)[i] = r;
}

// ---- W [K][N] fp32 -> Wt [N][K] bf16, 64x64 LDS tiles ----
__global__ __launch_bounds__(256) void wtrans(const float* __restrict__ w0, const float* __restrict__ w1,
                                              const float* __restrict__ w2, const float* __restrict__ w3,
                                              unsigned short* __restrict__ o0, unsigned short* __restrict__ o1,
                                              unsigned short* __restrict__ o2, unsigned short* __restrict__ o3) {
  __shared__ float tile[64][65];
  const float* src; unsigned short* dst;
  switch (blockIdx.z) {
    case 0: src = w0; dst = o0; break;
    case 1: src = w1; dst = o1; break;
    case 2: src = w2; dst = o2; break;
    default: src = w3; dst = o3; break;
  }
  const int k0 = blockIdx.y * 64, n0 = blockIdx.x * 64;
  const int c = threadIdx.x & 63, r0 = threadIdx.x >> 6;
#pragma unroll
  for (int i = 0; i < 16; ++i) {
    int r = r0 + i * 4;
    tile[r][c] = src[(size_t)(k0 + r) * EMBED + n0 + c];
  }
  __syncthreads();
#pragma unroll
  for (int i = 0; i < 16; ++i) {
    int nr = r0 + i * 4;
    dst[(size_t)(n0 + nr) * EMBED + k0 + c] = f2bf(tile[c][nr]);
  }
}

// ---- shared GEMM core: C[128x128 tile] = A @ Bt^T + bias, then *oscale ----
// A bf16 [M][K]; Bt bf16 [N][K]. Staging via global_load_lds (m97 pattern).
// mode 0: bf16 scatter to [B*H][S][D]; mode 1: fp32 row-major;
// mode 2: bf16 V^T scatter to [B*H][D][S], 4 s-packed per 8B store.
__device__ __forceinline__ void gemm_core(const unsigned short* __restrict__ A,
                                          const unsigned short* __restrict__ Bt,
                                          const float* __restrict__ bias,
                                          void* __restrict__ C, float oscale, int mode) {
  constexpr int K = EMBED;
  __shared__ __align__(16) unsigned short Alds[128 * 64];
  __shared__ __align__(16) unsigned short Blds[128 * 64];
  char* Ab8 = (char*)Alds; char* Bb8 = (char*)Blds;
  const char* AB = (const char*)A;
  const char* BB = (const char*)Bt;
  const int tid = threadIdx.x;
  const int lane = tid & 63, w = tid >> 6;
  const int wr = w >> 1, wc = w & 1;
  const int fr = lane & 15, fq = lane >> 4;
  const int m0 = blockIdx.y * 128, n0 = blockIdx.x * 128;
  const int bcol = (lane & 7) * 16;

  f32x4 acc[4][4];
#pragma unroll
  for (int m = 0; m < 4; ++m)
#pragma unroll
    for (int n = 0; n < 4; ++n) acc[m][n] = f32x4{0.f, 0.f, 0.f, 0.f};

  for (int k0 = 0; k0 < K; k0 += 64) {
    __syncthreads();
#pragma unroll
    for (int i = 0; i < 4; ++i) {
      int row = w * 32 + i * 8 + (lane >> 3);
      int sc_ = bcol ^ ((row & 7) << 4);
      gload16(AB + (size_t)(m0 + row) * (K * 2) + k0 * 2 + sc_, Ab8 + w * 4096 + i * 1024);
      gload16(BB + (size_t)(n0 + row) * (K * 2) + k0 * 2 + sc_, Bb8 + w * 4096 + i * 1024);
    }
    __syncthreads();  // drains vmcnt(0) -> tile staged
#pragma unroll
    for (int ks = 0; ks < 2; ++ks) {
      bf16x8 af[4], bfr[4];
#pragma unroll
      for (int m = 0; m < 4; ++m) {
        int ar = wr * 64 + m * 16 + fr;
        af[m] = *reinterpret_cast<const bf16x8*>(Ab8 + swz(ar, ks * 64 + fq * 16));
      }
#pragma unroll
      for (int n = 0; n < 4; ++n) {
        int br = wc * 64 + n * 16 + fr;
        bfr[n] = *reinterpret_cast<const bf16x8*>(Bb8 + swz(br, ks * 64 + fq * 16));
      }
#pragma unroll
      for (int m = 0; m < 4; ++m)
#pragma unroll
        for (int n = 0; n < 4; ++n)
          acc[m][n] = __builtin_amdgcn_mfma_f32_16x16x32_bf16(af[m], bfr[n], acc[m][n], 0, 0, 0);
    }
  }

#pragma unroll
  for (int n = 0; n < 4; ++n) {
    int col = n0 + wc * 64 + n * 16 + fr;
    float bv = bias[col];
#pragma unroll
    for (int m = 0; m < 4; ++m) {
      int rowb = m0 + wr * 64 + m * 16 + fq * 4;
      if (mode == 2) {
        int b = rowb >> 11, s0 = rowb & (SEQ - 1);
        int h = col >> 6, d = col & 63;
        int2 pk;
        pk.x = cvtpk_bf16((acc[m][n][0] + bv) * oscale, (acc[m][n][1] + bv) * oscale);
        pk.y = cvtpk_bf16((acc[m][n][2] + bv) * oscale, (acc[m][n][3] + bv) * oscale);
        *reinterpret_cast<int2*>(
            &reinterpret_cast<unsigned short*>(C)[((size_t)((b * NHEAD + h) * HDIM + d)) * SEQ + s0]) = pk;
      } else if (mode == 0) {
#pragma unroll
        for (int r = 0; r < 4; ++r) {
          int row = rowb + r;
          float v = (acc[m][n][r] + bv) * oscale;
          int b = row >> 11, s = row & (SEQ - 1), h = col >> 6, d = col & 63;
          reinterpret_cast<unsigned short*>(C)[((size_t)((b * NHEAD + h) * SEQ + s) << 6) + d] = f2bf(v);
        }
      } else {
#pragma unroll
        for (int r = 0; r < 4; ++r)
          reinterpret_cast<float*>(C)[(size_t)(rowb + r) * EMBED + col] = acc[m][n][r] + bv;
      }
    }
  }
}

// fused QKV projection: blockIdx.z picks {Q, K, V}; 768 blocks = 3/CU.
__global__ __launch_bounds__(256) void gemm_qkv(
    const unsigned short* __restrict__ Xq, const unsigned short* __restrict__ Xk,
    const unsigned short* __restrict__ Xv,
    const unsigned short* __restrict__ Wqt, const unsigned short* __restrict__ Wkt,
    const unsigned short* __restrict__ Wvt,
    const float* __restrict__ bq, const float* __restrict__ bk, const float* __restrict__ bv,
    unsigned short* __restrict__ Qb, unsigned short* __restrict__ Kb,
    unsigned short* __restrict__ Vtb, float qscale) {
  switch (blockIdx.z) {
    case 0: gemm_core(Xq, Wqt, bq, Qb, qscale, 0); break;
    case 1: gemm_core(Xk, Wkt, bk, Kb, 1.0f, 0); break;
    default: gemm_core(Xv, Wvt, bv, Vtb, 1.0f, 2); break;
  }
}

__global__ __launch_bounds__(256) void gemm_out(const unsigned short* __restrict__ A,
                                                const unsigned short* __restrict__ Bt,
                                                const float* __restrict__ bias,
                                                float* __restrict__ C) {
  gemm_core(A, Bt, bias, C, 1.0f, 1);
}

// ---- flash attention ----
// Q,K bf16 [B*H][S][D] (Q pre-scaled by log2e/8); Vt bf16 [B*H][D][S].
// Swapped QK^T: sc = mfma(K,Q) -> S^T, all 64 k-scores for q=fr in-lane.
// T14 reg-staged double buffer: global->regs issued before compute (latency
// hides under QK/softmax/PV), ds_write to the other buffer after compute,
// one __syncthreads per tile. No manual waitcnt (register deps order loads).
// Defer-max: skip O-rescale while tile max stays within 2^8 of running max.
__global__ __launch_bounds__(256) void attn(const unsigned short* __restrict__ Q,
                                            const unsigned short* __restrict__ Kk,
                                            const unsigned short* __restrict__ Vt,
                                            unsigned short* __restrict__ AO) {
  __shared__ __align__(16) unsigned short Klds[2][64 * 64];
  __shared__ __align__(16) unsigned short Vlds[2][64 * 64];  // [d][k]
  __shared__ __align__(16) unsigned short Plds[4][16 * 64];
  const int tid = threadIdx.x, lane = tid & 63, w = tid >> 6;
  const int fr = lane & 15, fq = lane >> 4;
  char* Pb8 = (char*)&Plds[w][0];

  // XCD swizzle: all 32 q-blocks of a head on one XCD (round-robin lin%8).
  const int lin = blockIdx.x;
  const int head = (lin & 7) * 4 + ((lin >> 3) & 3);
  const int q0 = (lin >> 5) * 64;
  const size_t hb = (size_t)head * SEQ * HDIM;
  const unsigned short* Qh = Q + hb;
  const char* KhB = (const char*)(Kk + hb);
  const char* VhB = (const char*)(Vt + hb);  // rows d, 4096B each

  // staging addressing (both-sides swizzle, rule #21):
  //   global col-byte: ((lane&7)*16) ^ ((lane>>3)<<4)   [loop-invariant]
  //   LDS write: linear, base + lane*16  -> reads use swz(row, bcol)
  const int gsc = ((lane & 7) * 16) ^ ((lane >> 3) << 4);
  const int row0 = w * 16 + (lane >> 3);       // i=0 row; i=1 adds 8
  const int lwr = w * 2048 + lane * 16;        // LDS write byte offset, i=0

  int4 kreg0, kreg1, vreg0, vreg1;
#define LOADREGS(kt_)                                                                  \
  {                                                                                    \
    kreg0 = *reinterpret_cast<const int4*>(KhB + (size_t)((kt_)*64 + row0) * 128 + gsc);       \
    kreg1 = *reinterpret_cast<const int4*>(KhB + (size_t)((kt_)*64 + row0 + 8) * 128 + gsc);   \
    vreg0 = *reinterpret_cast<const int4*>(VhB + (size_t)row0 * (SEQ * 2) + (kt_)*128 + gsc);  \
    vreg1 = *reinterpret_cast<const int4*>(VhB + (size_t)(row0 + 8) * (SEQ * 2) + (kt_)*128 + gsc); \
  }
#define WRITEREGS(b_)                                                 \
  {                                                                   \
    *reinterpret_cast<int4*>((char*)Klds[b_] + lwr) = kreg0;          \
    *reinterpret_cast<int4*>((char*)Klds[b_] + lwr + 1024) = kreg1;   \
    *reinterpret_cast<int4*>((char*)Vlds[b_] + lwr) = vreg0;          \
    *reinterpret_cast<int4*>((char*)Vlds[b_] + lwr + 1024) = vreg1;   \
  }

  bf16x8 qf[2];
  {
    size_t qoff = (size_t)(q0 + w * 16 + fr) * HDIM + fq * 8;
    qf[0] = *reinterpret_cast<const bf16x8*>(&Qh[qoff]);
    qf[1] = *reinterpret_cast<const bf16x8*>(&Qh[qoff + 32]);
  }
  f32x4 oacc[4];
#pragma unroll
  for (int n = 0; n < 4; ++n) oacc[n] = f32x4{0.f, 0.f, 0.f, 0.f};
  float mrow = -1e30f, lrow = 0.f;
  const int rsrc = (fq << 4) + (fq << 2);  // lane fq*16 + fq*4 (+rr): stats for q=fq*4+rr

  LOADREGS(0);
  WRITEREGS(0);
  __syncthreads();

  for (int kt = 0; kt < SEQ / 64; ++kt) {
    const int cur = kt & 1;
    char* Kb8 = (char*)Klds[cur];
    char* Vb8 = (char*)Vlds[cur];
    const bool more = (kt + 1 < SEQ / 64);
    if (more) LOADREGS(kt + 1);  // async: latency hides under this tile's compute

    // S^T = K·Q^T: sc[n] rows k = n*16+fq*4+r, col q = fr (log2 domain)
    f32x4 sc[4];
#pragma unroll
    for (int n = 0; n < 4; ++n) {
      int kr = n * 16 + fr;
      bf16x8 k0 = *reinterpret_cast<const bf16x8*>(Kb8 + swz(kr, fq * 16));
      bf16x8 k1 = *reinterpret_cast<const bf16x8*>(Kb8 + swz(kr, 64 + fq * 16));
      f32x4 a = f32x4{0.f, 0.f, 0.f, 0.f};
      a = __builtin_amdgcn_mfma_f32_16x16x32_bf16(k0, qf[0], a, 0, 0, 0);
      a = __builtin_amdgcn_mfma_f32_16x16x32_bf16(k1, qf[1], a, 0, 0, 0);
      sc[n] = a;
    }

    // tile max for this lane's q (=fr): 16 in-lane + 2 cross-lane
    float mx0 = fmaxf(fmaxf(sc[0][0], sc[0][1]), fmaxf(sc[0][2], sc[0][3]));
    float mx1 = fmaxf(fmaxf(sc[1][0], sc[1][1]), fmaxf(sc[1][2], sc[1][3]));
    float mx2 = fmaxf(fmaxf(sc[2][0], sc[2][1]), fmaxf(sc[2][2], sc[2][3]));
    float mx3 = fmaxf(fmaxf(sc[3][0], sc[3][1]), fmaxf(sc[3][2], sc[3][3]));
    float mt = fmaxf(fmaxf(mx0, mx1), fmaxf(mx2, mx3));
    mt = fmaxf(mt, __shfl_xor(mt, 16));
    mt = fmaxf(mt, __shfl_xor(mt, 32));

    // T13 defer-max: only rescale when some row's max grew past 2^8 headroom
    if (!__all(mt <= mrow + 8.0f)) {
      float mn = fmaxf(mrow, mt);
      float resc = exp2f(mrow - mn);
      lrow *= resc;
      float rq[4];
#pragma unroll
      for (int rr = 0; rr < 4; ++rr) rq[rr] = __shfl(resc, rsrc + rr, 64);
#pragma unroll
      for (int n = 0; n < 4; ++n)
#pragma unroll
        for (int rr = 0; rr < 4; ++rr) oacc[n][rr] *= rq[rr];
      mrow = mn;
    }

    float p[4][4];
    float ps = 0.f;
#pragma unroll
    for (int n = 0; n < 4; ++n)
#pragma unroll
      for (int r = 0; r < 4; ++r) {
        p[n][r] = exp2f(sc[n][r] - mrow);
        ps += p[n][r];
      }
    ps += __shfl_xor(ps, 16);
    ps += __shfl_xor(ps, 32);
    lrow += ps;

    // P -> Plds[q=fr][k] (swizzled), 4x ds_write_b64 via cvt_pk; k = n*16+fq*4+r
#pragma unroll
    for (int n = 0; n < 4; ++n) {
      int2 pk;
      pk.x = cvtpk_bf16(p[n][0], p[n][1]);
      pk.y = cvtpk_bf16(p[n][2], p[n][3]);
      *reinterpret_cast<int2*>(Pb8 + swz(fr, n * 32 + fq * 8)) = pk;
    }

    bf16x8 pa0 = *reinterpret_cast<const bf16x8*>(Pb8 + swz(fr, fq * 16));
    bf16x8 pa1 = *reinterpret_cast<const bf16x8*>(Pb8 + swz(fr, 64 + fq * 16));
#pragma unroll
    for (int n = 0; n < 4; ++n) {
      int dr = n * 16 + fr;
      bf16x8 vb0 = *reinterpret_cast<const bf16x8*>(Vb8 + swz(dr, fq * 16));
      bf16x8 vb1 = *reinterpret_cast<const bf16x8*>(Vb8 + swz(dr, 64 + fq * 16));
      oacc[n] = __builtin_amdgcn_mfma_f32_16x16x32_bf16(pa0, vb0, oacc[n], 0, 0, 0);
      oacc[n] = __builtin_amdgcn_mfma_f32_16x16x32_bf16(pa1, vb1, oacc[n], 0, 0, 0);
    }

    if (more) WRITEREGS(cur ^ 1);  // compiler waits loads via reg dep; buffer
                                   // free: all waves passed last barrier
    __syncthreads();
  }
#undef LOADREGS
#undef WRITEREGS

  const int b = head >> 4, h = head & 15;
  float lr[4];
#pragma unroll
  for (int rr = 0; rr < 4; ++rr) lr[rr] = __shfl(lrow, rsrc + rr, 64);
#pragma unroll
  for (int rr = 0; rr < 4; ++rr) {
    float inv = 1.0f / lr[rr];
    int srow = q0 + w * 16 + fq * 4 + rr;
    size_t ob = (size_t)(b * SEQ + srow) * EMBED + h * 64;
#pragma unroll
    for (int n = 0; n < 4; ++n) AO[ob + n * 16 + fr] = f2bf(oacc[n][rr] * inv);
  }
}

extern "C" void kernel_launch(void* const* d_in, const int* in_sizes, int n_in,
                              void* d_out, int out_size, void* d_ws, size_t ws_size,
                              hipStream_t stream) {
  const float* q32 = (const float*)d_in[0];
  const float* k32 = (const float*)d_in[1];
  const float* v32 = (const float*)d_in[2];
  const float* Wq = (const float*)d_in[3]; const float* bq = (const float*)d_in[4];
  const float* Wk = (const float*)d_in[5]; const float* bk = (const float*)d_in[6];
  const float* Wv = (const float*)d_in[7]; const float* bv = (const float*)d_in[8];
  const float* Wo = (const float*)d_in[9]; const float* bo = (const float*)d_in[10];
  float* out = (float*)d_out;

  char* ws = (char*)d_ws;
  const size_t MB = 1u << 20;
  unsigned short* Xq  = (unsigned short*)(ws + 0 * MB);
  unsigned short* Xk  = (unsigned short*)(ws + 8 * MB);
  unsigned short* Xv  = (unsigned short*)(ws + 16 * MB);
  unsigned short* Wqt = (unsigned short*)(ws + 24 * MB);
  unsigned short* Wkt = (unsigned short*)(ws + 26 * MB);
  unsigned short* Wvt = (unsigned short*)(ws + 28 * MB);
  unsigned short* Wot = (unsigned short*)(ws + 30 * MB);
  unsigned short* Qb  = (unsigned short*)(ws + 32 * MB);
  unsigned short* Kb  = (unsigned short*)(ws + 40 * MB);
  unsigned short* Vtb = (unsigned short*)(ws + 48 * MB);
  unsigned short* AO  = Xq;  // safe: GEMM-Q (sole Xq reader) completes before attn writes

  const int n8 = (MROWS * EMBED) / 8;  // 524288
  cvt_f32_bf16<<<dim3(n8 / 256, 3), 256, 0, stream>>>(q32, k32, v32, Xq, Xk, Xv);
  wtrans<<<dim3(16, 16, 4), 256, 0, stream>>>(Wq, Wk, Wv, Wo, Wqt, Wkt, Wvt, Wot);

  const float qscale = 0.125f * 1.44269504088896340736f;  // (1/sqrt(64)) * log2(e)
  gemm_qkv<<<dim3(EMBED / 128, MROWS / 128, 3), 256, 0, stream>>>(
      Xq, Xk, Xv, Wqt, Wkt, Wvt, bq, bk, bv, Qb, Kb, Vtb, qscale);

  attn<<<dim3(SEQ / 64 * 32), 256, 0, stream>>>(Qb, Kb, Vtb, AO);

  gemm_out<<<dim3(EMBED / 128, MROWS / 128), 256, 0, stream>>>(AO, Wot, bo, out);
}